// Round 11
// baseline (21.828 us; speedup 1.0000x reference)
//
#include <hip/hip_runtime.h>
#include <hip/hip_bf16.h>

#define NPTS 1024
#define HID 128
#define KNN 10
#define PPB 4                  // points per block (block = PPB*256 threads)
#define FLT_MAX_ 3.402823466e+38f

// ---------------------------------------------------------------------------
// Kernel 1: build LUTs (epilogue folded) + repack points (folded, strided).
//   Td[v][c] = (sinusoid(v).Wd[c] + bd[c]) / 1024,  v in [0,256)
//   Ta[v][c] =  sinusoid(v).Wa[c] + ba[c],          v in [0,16)
//   P4[j]    = (x,y,z,0)
// grid: 272 blocks x 512 threads.
// ---------------------------------------------------------------------------
__global__ __launch_bounds__(512) void gse_build(
    const float* __restrict__ Wd, const float* __restrict__ bd,
    const float* __restrict__ Wa, const float* __restrict__ ba,
    const float* __restrict__ pts, int nP,
    float* __restrict__ Td, float* __restrict__ Ta, float4* __restrict__ P4) {
    const int blk = blockIdx.x;
    const int tid = threadIdx.x;

    // folded repack: 8 points per block per pass, strided for any nP
    if (tid < 8) {
        for (int idx = blk * 8 + tid; idx < nP; idx += 272 * 8) {
            P4[idx] = make_float4(pts[idx * 3 + 0], pts[idx * 3 + 1],
                                  pts[idx * 3 + 2], 0.0f);
        }
    }

    __shared__ float S[HID];
    __shared__ float part[512];
    const bool isA = (blk >= 256);
    const int v = isA ? blk - 256 : blk;
    const int c = tid & 127;
    const int seg = tid >> 7;               // 0..3

    if (tid < HID) {
        const int m = tid >> 1;
        const float dtm = expf((float)m * (float)(-9.210340371976184 / 64.0));
        const float arg = (float)v * dtm;
        S[tid] = (tid & 1) ? cosf(arg) : sinf(arg);
    }
    __syncthreads();

    const float* W = isA ? Wa : Wd;
    const float* wrow = W + c * HID + seg * 32;
    const float* srow = S + seg * 32;
    float acc = 0.0f;
    #pragma unroll
    for (int h = 0; h < 32; h += 4) {
        const float4 wv = *reinterpret_cast<const float4*>(wrow + h);
        acc += srow[h] * wv.x + srow[h + 1] * wv.y + srow[h + 2] * wv.z + srow[h + 3] * wv.w;
    }
    part[tid] = acc;
    __syncthreads();

    if (tid < HID) {
        const float s = (part[c] + part[c + 128]) + (part[c + 256] + part[c + 384]);
        if (isA) Ta[v * HID + c] = s + ba[c];
        else     Td[v * HID + c] = (s + bd[c]) * (1.0f / (float)NPTS);
    }
}

// ---------------------------------------------------------------------------
// Kernel 2: FOUR points per block (1024 threads = 4 x 4 waves).
//   grid = nP/4 -> 512 WGs, 2 blocks/CU x 16 waves = 32 waves/CU (100%).
//   R10 pipeline + phases 3/4 fused (per-pair unit-vector recompute,
//   bit-identical to R6/R8's passing kernels) -> one fewer barrier.
//   Candidates packed as u64 (fbits(d)<<32 | idx): one 64-bit compare =
//   exact (d, idx) lexicographic rank. Barrier parity between fast/fallback.
// ---------------------------------------------------------------------------
__global__ __launch_bounds__(1024, 8) void gse_main4(
    const float4* __restrict__ P4,      // (nP)
    const float* __restrict__ Td,       // (256, 128)
    const float* __restrict__ Ta,       // (16, 128)
    float* __restrict__ out) {          // (nP, 128)
    const int tid = threadIdx.x;        // 0..1023
    const int pt  = tid >> 8;           // 0..3  (point slot)
    const int t   = tid & 255;          // thread within point
    const int lane = tid & 63;
    const int w   = (tid >> 6) & 3;     // wave within point
    const int gid = blockIdx.x * PPB + pt;

    const int b = gid >> 10;
    const int i = gid & 1023;
    const float4* P = P4 + (size_t)b * NPTS;

    __shared__ int h4[PPB][4][256];
    __shared__ unsigned long long cand[PPB][64];
    __shared__ int nn[PPB][KNN];
    __shared__ float sums[PPB][256], mxs[PPB][256];
    __shared__ unsigned amask_s[PPB];
    __shared__ int ccnt[PPB];
    __shared__ int meta_s[PPB];

    {   // zero my point's hist (1024 ints over 256 threads)
        int* hf = (int*)h4[pt];
        hf[t] = 0; hf[t + 256] = 0; hf[t + 512] = 0; hf[t + 768] = 0;
    }
    if (t == 0) { amask_s[pt] = 0u; ccnt[pt] = 0; }
    const float4 p = P[i];
    __syncthreads();                                      // B1

    // ---- phase 1: 4 distances/lane + per-wave private hist ----
    float d4[4];
    int q4[4];
    const int jb = w * 256;
    #pragma unroll
    for (int s = 0; s < 4; ++s) {
        const int j = jb + s * 64 + lane;
        const float4 q = P[j];
        const float dx = p.x - q.x;
        const float dy = p.y - q.y;
        const float dz = p.z - q.z;
        const float dd = sqrtf(dx * dx + dy * dy + dz * dz);
        d4[s] = dd;
        float qq = rintf(dd / 0.2f);    // matches jnp.round (half-to-even)
        qq = fminf(fmaxf(qq, 0.0f), 255.0f);
        q4[s] = (int)qq;
        atomicAdd(&h4[pt][w][q4[s]], 1);
    }
    __syncthreads();                                      // B2

    // ---- merge the 4 per-wave hists ----
    const int hsum = h4[pt][0][t] + h4[pt][1][t] + h4[pt][2][t] + h4[pt][3][t];
    h4[pt][0][t] = hsum;
    __syncthreads();                                      // B3
    const int* hist = h4[pt][0];

    // ---- wave 0 (of each point): scan bins 0..63 + ballots -> meta ----
    if (w == 0) {
        int cum = hist[lane];
        #pragma unroll
        for (int off = 1; off < 64; off <<= 1) {
            const int n_ = __shfl_up(cum, off);
            if (lane >= off) cum += n_;
        }
        const unsigned long long bal = __ballot(cum >= KNN);
        const unsigned long long nz0 = __ballot(hist[lane] != 0);
        const unsigned long long nz1 = __ballot(hist[64 + lane] != 0);
        const unsigned long long nz2 = __ballot(hist[128 + lane] != 0);
        const unsigned long long nz3 = __ballot(hist[192 + lane] != 0);
        int maxbin;
        if (nz3)      maxbin = 192 + 63 - __clzll((long long)nz3);
        else if (nz2) maxbin = 128 + 63 - __clzll((long long)nz2);
        else if (nz1) maxbin = 64 + 63 - __clzll((long long)nz1);
        else          maxbin = 63 - __clzll((long long)nz0);
        int b10 = 0, c = 0;
        if (bal) { b10 = __ffsll(bal) - 1; c = __shfl(cum, b10); }
        const int fast = (bal != 0ull && c <= 64) ? 1 : 0;
        if (lane == 0) {
            meta_s[pt] = (b10 & 0xff) | ((fast ? c : 0) << 8)
                       | ((maxbin & 0xff) << 16) | (fast << 30);
        }
    }
    __syncthreads();                                      // B4
    const int meta = meta_s[pt];
    const int b10 = meta & 0xff;
    const int c = (meta >> 8) & 0xff;
    const int maxbin = (meta >> 16) & 0xff;
    const bool fast = ((meta >> 30) & 1) != 0;            // uniform per point

    if (fast) {
        // ---- ballot-base compaction of candidates (bin <= b10, c <= 64) ----
        #pragma unroll
        for (int s = 0; s < 4; ++s) {
            const bool pred = (q4[s] <= b10);
            const unsigned long long m = __ballot(pred);
            if (m) {
                int base = 0;
                if (lane == 0) base = atomicAdd(&ccnt[pt], __popcll(m));
                base = __shfl(base, 0);
                if (pred) {
                    const int pos = base + (int)__popcll(m & ((1ull << lane) - 1ull));
                    const int idx = jb + s * 64 + lane;
                    cand[pt][pos] = ((unsigned long long)__float_as_uint(d4[s]) << 32)
                                  | (unsigned)idx;
                }
            }
        }
        __syncthreads();                                  // B5
        if (t < c) {
            const unsigned long long my = cand[pt][t];
            int rank = 0;
            #pragma unroll 8
            for (int pp = 0; pp < c; ++pp) {
                rank += (cand[pt][pp] < my) ? 1 : 0;
            }
            if (rank < KNN) nn[pt][rank] = (int)(my & 0xffffffffu);
        }
        __syncthreads();                                  // B6
    } else {
        // ---- fallback: per-wave top-10, then 40-way u64 rank merge ----
        unsigned valid = 0xfu;
        unsigned long long keep = 0;
        for (int r = 0; r < KNN; ++r) {
            float bv = FLT_MAX_;
            int bi = 0x7fffffff;
            #pragma unroll
            for (int s = 0; s < 4; ++s) {
                if (valid & (1u << s)) {
                    const float v_ = d4[s];
                    const int id_ = jb + s * 64 + lane;
                    if (v_ < bv || (v_ == bv && id_ < bi)) { bv = v_; bi = id_; }
                }
            }
            #pragma unroll
            for (int off = 32; off > 0; off >>= 1) {
                const float ov = __shfl_xor(bv, off);
                const int oi = __shfl_xor(bi, off);
                if (ov < bv || (ov == bv && oi < bi)) { bv = ov; bi = oi; }
            }
            const int loc = bi - jb;
            if (loc >= 0 && loc < 256 && lane == (loc & 63)) valid &= ~(1u << (loc >> 6));
            if (lane == r) keep = ((unsigned long long)__float_as_uint(bv) << 32)
                                | (unsigned)bi;
        }
        if (lane < KNN) cand[pt][w * KNN + lane] = keep;
        __syncthreads();                                  // B5
        if (t < 4 * KNN) {
            const unsigned long long my = cand[pt][t];
            int rank = 0;
            for (int pp = 0; pp < 4 * KNN; ++pp) {
                rank += (cand[pt][pp] < my) ? 1 : 0;
            }
            if (rank < KNN) nn[pt][rank] = (int)(my & 0xffffffffu);
        }
        __syncthreads();                                  // B6
    }

    // ---- phases 3+4 fused: each pair recomputes both unit vectors ----
    if (t < KNN * KNN) {
        const int k = t / KNN, l = t % KNN;
        const int jk = nn[pt][k], jl = nn[pt][l];
        const float4 qk = P[jk];
        const float4 ql = P[jl];
        const float kx = qk.x - p.x;
        const float ky = qk.y - p.y;
        const float kz = qk.z - p.z;
        const float dk = sqrtf(kx * kx + ky * ky + kz * kz) + 1e-8f;
        const float lx = ql.x - p.x;
        const float ly = ql.y - p.y;
        const float lz = ql.z - p.z;
        const float dl = sqrtf(lx * lx + ly * ly + lz * lz) + 1e-8f;
        float cc = (kx / dk) * (lx / dl) + (ky / dk) * (ly / dl) + (kz / dk) * (lz / dl);
        cc = fminf(fmaxf(cc, -1.0f), 1.0f);
        const float ang = acosf(cc);
        float q = rintf(ang * (float)(180.0 / (15.0 * M_PI)));
        q = fminf(fmaxf(q, 0.0f), 15.0f);
        atomicOr(&amask_s[pt], 1u << (int)q);
    }
    __syncthreads();                                      // B7

    // ---- phase 5: split even/odd bins + low/high mask across half-points ----
    const unsigned am = amask_s[pt];
    const int c7 = t & 127;
    const int half = t >> 7;
    float s = 0.0f;
    const float* tdc = Td + c7;
    #pragma unroll 4
    for (int v = half; v <= maxbin; v += 2) {
        s += (float)hist[v] * tdc[v * HID];   // zero bins add exact 0.0f
    }
    float mx = -FLT_MAX_;
    const float* tac = Ta + c7;
    #pragma unroll
    for (int v = 0; v < 8; ++v) {
        const int vv = half * 8 + v;
        const float tv = tac[vv * HID];
        if (am & (1u << vv)) mx = fmaxf(mx, tv);
    }
    sums[pt][t] = s;
    mxs[pt][t] = mx;
    __syncthreads();                                      // B8
    if (t < HID) {
        out[(size_t)gid * HID + t] =
            (sums[pt][t] + sums[pt][t + 128]) + fmaxf(mxs[pt][t], mxs[pt][t + 128]);
    }
}

// ---------------------------------------------------------------------------
// Fallback single-point kernel (R10, proven) for nP not divisible by PPB.
// ---------------------------------------------------------------------------
__global__ __launch_bounds__(256, 8) void gse_main(
    const float4* __restrict__ P4,
    const float* __restrict__ Td,
    const float* __restrict__ Ta,
    float* __restrict__ out) {
    const int gid = blockIdx.x;
    const int b = gid >> 10;
    const int i = gid & 1023;
    const float4* P = P4 + (size_t)b * NPTS;
    const int tid = threadIdx.x;
    const int lane = tid & 63;
    const int w = tid >> 6;

    __shared__ int h4[4][256];
    __shared__ unsigned long long cand[64];
    __shared__ int nn[KNN];
    __shared__ float sums[256], mxs[256];
    __shared__ unsigned amask_s;
    __shared__ int ccnt;
    __shared__ int meta_s;

    {
        int* hf = (int*)h4;
        hf[tid] = 0; hf[tid + 256] = 0; hf[tid + 512] = 0; hf[tid + 768] = 0;
    }
    if (tid == 0) { amask_s = 0u; ccnt = 0; }
    const float4 p = P[i];
    __syncthreads();

    float d4[4];
    int q4[4];
    const int jb = w * 256;
    #pragma unroll
    for (int s = 0; s < 4; ++s) {
        const int j = jb + s * 64 + lane;
        const float4 q = P[j];
        const float dx = p.x - q.x;
        const float dy = p.y - q.y;
        const float dz = p.z - q.z;
        const float dd = sqrtf(dx * dx + dy * dy + dz * dz);
        d4[s] = dd;
        float qq = rintf(dd / 0.2f);
        qq = fminf(fmaxf(qq, 0.0f), 255.0f);
        q4[s] = (int)qq;
        atomicAdd(&h4[w][q4[s]], 1);
    }
    __syncthreads();

    const int hsum = h4[0][tid] + h4[1][tid] + h4[2][tid] + h4[3][tid];
    h4[0][tid] = hsum;
    __syncthreads();
    const int* hist = h4[0];

    if (w == 0) {
        int cum = hist[lane];
        #pragma unroll
        for (int off = 1; off < 64; off <<= 1) {
            const int n_ = __shfl_up(cum, off);
            if (lane >= off) cum += n_;
        }
        const unsigned long long bal = __ballot(cum >= KNN);
        const unsigned long long nz0 = __ballot(hist[lane] != 0);
        const unsigned long long nz1 = __ballot(hist[64 + lane] != 0);
        const unsigned long long nz2 = __ballot(hist[128 + lane] != 0);
        const unsigned long long nz3 = __ballot(hist[192 + lane] != 0);
        int maxbin;
        if (nz3)      maxbin = 192 + 63 - __clzll((long long)nz3);
        else if (nz2) maxbin = 128 + 63 - __clzll((long long)nz2);
        else if (nz1) maxbin = 64 + 63 - __clzll((long long)nz1);
        else          maxbin = 63 - __clzll((long long)nz0);
        int b10 = 0, c = 0;
        if (bal) { b10 = __ffsll(bal) - 1; c = __shfl(cum, b10); }
        const int fast = (bal != 0ull && c <= 64) ? 1 : 0;
        if (lane == 0) {
            meta_s = (b10 & 0xff) | ((fast ? c : 0) << 8)
                   | ((maxbin & 0xff) << 16) | (fast << 30);
        }
    }
    __syncthreads();
    const int meta = meta_s;
    const int b10 = meta & 0xff;
    const int c = (meta >> 8) & 0xff;
    const int maxbin = (meta >> 16) & 0xff;
    const bool fast = ((meta >> 30) & 1) != 0;

    if (fast) {
        #pragma unroll
        for (int s = 0; s < 4; ++s) {
            const bool pred = (q4[s] <= b10);
            const unsigned long long m = __ballot(pred);
            if (m) {
                int base = 0;
                if (lane == 0) base = atomicAdd(&ccnt, __popcll(m));
                base = __shfl(base, 0);
                if (pred) {
                    const int pos = base + (int)__popcll(m & ((1ull << lane) - 1ull));
                    const int idx = jb + s * 64 + lane;
                    cand[pos] = ((unsigned long long)__float_as_uint(d4[s]) << 32)
                              | (unsigned)idx;
                }
            }
        }
        __syncthreads();
        if (tid < c) {
            const unsigned long long my = cand[tid];
            int rank = 0;
            #pragma unroll 8
            for (int pp = 0; pp < c; ++pp) rank += (cand[pp] < my) ? 1 : 0;
            if (rank < KNN) nn[rank] = (int)(my & 0xffffffffu);
        }
        __syncthreads();
    } else {
        unsigned valid = 0xfu;
        unsigned long long keep = 0;
        for (int r = 0; r < KNN; ++r) {
            float bv = FLT_MAX_;
            int bi = 0x7fffffff;
            #pragma unroll
            for (int s = 0; s < 4; ++s) {
                if (valid & (1u << s)) {
                    const float v_ = d4[s];
                    const int id_ = jb + s * 64 + lane;
                    if (v_ < bv || (v_ == bv && id_ < bi)) { bv = v_; bi = id_; }
                }
            }
            #pragma unroll
            for (int off = 32; off > 0; off >>= 1) {
                const float ov = __shfl_xor(bv, off);
                const int oi = __shfl_xor(bi, off);
                if (ov < bv || (ov == bv && oi < bi)) { bv = ov; bi = oi; }
            }
            const int loc = bi - jb;
            if (loc >= 0 && loc < 256 && lane == (loc & 63)) valid &= ~(1u << (loc >> 6));
            if (lane == r) keep = ((unsigned long long)__float_as_uint(bv) << 32)
                                | (unsigned)bi;
        }
        if (lane < KNN) cand[w * KNN + lane] = keep;
        __syncthreads();
        if (tid < 4 * KNN) {
            const unsigned long long my = cand[tid];
            int rank = 0;
            for (int pp = 0; pp < 4 * KNN; ++pp) rank += (cand[pp] < my) ? 1 : 0;
            if (rank < KNN) nn[rank] = (int)(my & 0xffffffffu);
        }
        __syncthreads();
    }

    if (tid < KNN * KNN) {
        const int k = tid / KNN, l = tid % KNN;
        const int jk = nn[k], jl = nn[l];
        const float4 qk = P[jk];
        const float4 ql = P[jl];
        const float kx = qk.x - p.x;
        const float ky = qk.y - p.y;
        const float kz = qk.z - p.z;
        const float dk = sqrtf(kx * kx + ky * ky + kz * kz) + 1e-8f;
        const float lx = ql.x - p.x;
        const float ly = ql.y - p.y;
        const float lz = ql.z - p.z;
        const float dl = sqrtf(lx * lx + ly * ly + lz * lz) + 1e-8f;
        float cc = (kx / dk) * (lx / dl) + (ky / dk) * (ly / dl) + (kz / dk) * (lz / dl);
        cc = fminf(fmaxf(cc, -1.0f), 1.0f);
        const float ang = acosf(cc);
        float q = rintf(ang * (float)(180.0 / (15.0 * M_PI)));
        q = fminf(fmaxf(q, 0.0f), 15.0f);
        atomicOr(&amask_s, 1u << (int)q);
    }
    __syncthreads();

    const unsigned am = amask_s;
    const int c7 = tid & 127;
    const int half = tid >> 7;
    float s = 0.0f;
    const float* tdc = Td + c7;
    #pragma unroll 4
    for (int v = half; v <= maxbin; v += 2) {
        s += (float)hist[v] * tdc[v * HID];
    }
    float mx = -FLT_MAX_;
    const float* tac = Ta + c7;
    #pragma unroll
    for (int v = 0; v < 8; ++v) {
        const int vv = half * 8 + v;
        const float tv = tac[vv * HID];
        if (am & (1u << vv)) mx = fmaxf(mx, tv);
    }
    sums[tid] = s;
    mxs[tid] = mx;
    __syncthreads();
    if (tid < HID) {
        out[(size_t)gid * HID + tid] =
            (sums[tid] + sums[tid + 128]) + fmaxf(mxs[tid], mxs[tid + 128]);
    }
}

extern "C" void kernel_launch(void* const* d_in, const int* in_sizes, int n_in,
                              void* d_out, int out_size, void* d_ws, size_t ws_size,
                              hipStream_t stream) {
    const float* pts = (const float*)d_in[0];
    const float* Wd  = (const float*)d_in[1];
    const float* bd  = (const float*)d_in[2];
    const float* Wa  = (const float*)d_in[3];
    const float* ba  = (const float*)d_in[4];
    float* out = (float*)d_out;

    const int B = in_sizes[0] / (NPTS * 3);
    const int nP = B * NPTS;

    float* Td = (float*)d_ws;                        // 256*128*4 = 128 KiB
    float* Ta = Td + 256 * HID;                      // 16*128*4  =   8 KiB
    float4* P4 = (float4*)(Ta + 16 * HID);           // nP*16 B

    gse_build<<<272, 512, 0, stream>>>(Wd, bd, Wa, ba, pts, nP, Td, Ta, P4);
    if (nP % PPB == 0) {
        gse_main4<<<nP / PPB, PPB * 256, 0, stream>>>(P4, Td, Ta, out);
    } else {
        gse_main<<<nP, 256, 0, stream>>>(P4, Td, Ta, out);
    }
}

// Round 12
// 21.105 us; speedup vs baseline: 1.0342x; 1.0342x over previous
//
#include <hip/hip_runtime.h>
#include <hip/hip_bf16.h>

#define NPTS 1024
#define HID 128
#define KNN 10
#define PPB 2                  // points per block (block = PPB*256 threads)
#define FLT_MAX_ 3.402823466e+38f

// ---------------------------------------------------------------------------
// Kernel 1: build LUTs (epilogue folded) + repack points. 256 WGs = ONE
// dispatch round on 256 CUs (was 272 -> two rounds). Blocks 0..15 build BOTH
// Td[v] and Ta[v] (same sinusoid S; different W and bias).
//   Td[v][c] = (sinusoid(v).Wd[c] + bd[c]) / 1024,  v in [0,256)
//   Ta[v][c] =  sinusoid(v).Wa[c] + ba[c],          v in [0,16)
// ---------------------------------------------------------------------------
__global__ __launch_bounds__(512) void gse_build(
    const float* __restrict__ Wd, const float* __restrict__ bd,
    const float* __restrict__ Wa, const float* __restrict__ ba,
    const float* __restrict__ pts, int nP,
    float* __restrict__ Td, float* __restrict__ Ta, float4* __restrict__ P4) {
    const int blk = blockIdx.x;             // 0..255
    const int tid = threadIdx.x;

    // folded repack: 8 points per block per pass, strided for any nP
    if (tid < 8) {
        for (int idx = blk * 8 + tid; idx < nP; idx += 256 * 8) {
            P4[idx] = make_float4(pts[idx * 3 + 0], pts[idx * 3 + 1],
                                  pts[idx * 3 + 2], 0.0f);
        }
    }

    __shared__ float S[HID];
    __shared__ float part[512];
    const int v = blk;
    const int c = tid & 127;
    const int seg = tid >> 7;               // 0..3

    if (tid < HID) {
        const int m = tid >> 1;
        const float dtm = expf((float)m * (float)(-9.210340371976184 / 64.0));
        const float arg = (float)v * dtm;
        S[tid] = (tid & 1) ? cosf(arg) : sinf(arg);
    }
    __syncthreads();

    {   // Td row v
        const float* wrow = Wd + c * HID + seg * 32;
        const float* srow = S + seg * 32;
        float acc = 0.0f;
        #pragma unroll
        for (int h = 0; h < 32; h += 4) {
            const float4 wv = *reinterpret_cast<const float4*>(wrow + h);
            acc += srow[h] * wv.x + srow[h + 1] * wv.y
                 + srow[h + 2] * wv.z + srow[h + 3] * wv.w;
        }
        part[tid] = acc;
    }
    __syncthreads();
    if (tid < HID) {
        const float s = (part[c] + part[c + 128]) + (part[c + 256] + part[c + 384]);
        Td[v * HID + c] = (s + bd[c]) * (1.0f / (float)NPTS);
    }

    if (blk < 16) {                         // also Ta row v (same S)
        __syncthreads();                    // Td-readers done with part
        const float* wrow = Wa + c * HID + seg * 32;
        const float* srow = S + seg * 32;
        float acc = 0.0f;
        #pragma unroll
        for (int h = 0; h < 32; h += 4) {
            const float4 wv = *reinterpret_cast<const float4*>(wrow + h);
            acc += srow[h] * wv.x + srow[h + 1] * wv.y
                 + srow[h + 2] * wv.z + srow[h + 3] * wv.w;
        }
        part[tid] = acc;
        __syncthreads();
        if (tid < HID) {
            const float s = (part[c] + part[c + 128]) + (part[c + 256] + part[c + 384]);
            Ta[v * HID + c] = s + ba[c];
        }
    }
}

// ---------------------------------------------------------------------------
// Kernel 2: TWO points per block (512 threads = 2 x 4 waves), grid = nP/2.
//   4 blocks/CU x 8 waves = 32 waves/CU (100%). Wave-specialized tail:
//     B5->B6: wave2 rank-select  ||  waves0-1 Td-dot part 1
//     B6->B7: wave3 angles       ||  waves0-1 Td-dot part 2
//     after B7: waves0-1 Ta-max + direct out write (no sums/mxs LDS)
//   7 barriers (was 9); barrier parity kept between fast/fallback branches.
//   Candidates packed as u64 (fbits(d)<<32 | idx): one 64-bit compare =
//   exact (d, idx) lexicographic rank.
// ---------------------------------------------------------------------------
__global__ __launch_bounds__(512, 8) void gse_main2(
    const float4* __restrict__ P4,      // (nP)
    const float* __restrict__ Td,       // (256, 128)
    const float* __restrict__ Ta,       // (16, 128)
    float* __restrict__ out) {          // (nP, 128)
    const int tid = threadIdx.x;        // 0..511
    const int pt  = tid >> 8;           // 0..1  (point slot)
    const int t   = tid & 255;          // thread within point
    const int lane = tid & 63;
    const int w   = (tid >> 6) & 3;     // wave within point
    const int gid = blockIdx.x * PPB + pt;

    const int b = gid >> 10;
    const int i = gid & 1023;
    const float4* P = P4 + (size_t)b * NPTS;

    __shared__ int h4[PPB][4][256];
    __shared__ unsigned long long cand[PPB][64];
    __shared__ int nn[PPB][KNN];
    __shared__ unsigned amask_s[PPB];
    __shared__ int ccnt[PPB];
    __shared__ int meta_s[PPB];

    {   // zero my point's hist (1024 ints over 256 threads)
        int* hf = (int*)h4[pt];
        hf[t] = 0; hf[t + 256] = 0; hf[t + 512] = 0; hf[t + 768] = 0;
    }
    if (t == 0) { ccnt[pt] = 0; }
    const float4 p = P[i];
    __syncthreads();                                      // B1

    // ---- phase 1: 4 distances/lane + per-wave private hist ----
    float d4[4];
    int q4[4];
    const int jb = w * 256;
    #pragma unroll
    for (int s = 0; s < 4; ++s) {
        const int j = jb + s * 64 + lane;
        const float4 q = P[j];
        const float dx = p.x - q.x;
        const float dy = p.y - q.y;
        const float dz = p.z - q.z;
        const float dd = sqrtf(dx * dx + dy * dy + dz * dz);
        d4[s] = dd;
        float qq = rintf(dd / 0.2f);    // matches jnp.round (half-to-even)
        qq = fminf(fmaxf(qq, 0.0f), 255.0f);
        q4[s] = (int)qq;
        atomicAdd(&h4[pt][w][q4[s]], 1);
    }
    __syncthreads();                                      // B2

    // ---- merge the 4 per-wave hists ----
    const int hsum = h4[pt][0][t] + h4[pt][1][t] + h4[pt][2][t] + h4[pt][3][t];
    h4[pt][0][t] = hsum;
    __syncthreads();                                      // B3
    const int* hist = h4[pt][0];

    // ---- wave 0 (of each point): scan bins 0..63 + ballots -> meta ----
    if (w == 0) {
        int cum = hist[lane];
        #pragma unroll
        for (int off = 1; off < 64; off <<= 1) {
            const int n_ = __shfl_up(cum, off);
            if (lane >= off) cum += n_;
        }
        const unsigned long long bal = __ballot(cum >= KNN);
        const unsigned long long nz0 = __ballot(hist[lane] != 0);
        const unsigned long long nz1 = __ballot(hist[64 + lane] != 0);
        const unsigned long long nz2 = __ballot(hist[128 + lane] != 0);
        const unsigned long long nz3 = __ballot(hist[192 + lane] != 0);
        int maxbin;
        if (nz3)      maxbin = 192 + 63 - __clzll((long long)nz3);
        else if (nz2) maxbin = 128 + 63 - __clzll((long long)nz2);
        else if (nz1) maxbin = 64 + 63 - __clzll((long long)nz1);
        else          maxbin = 63 - __clzll((long long)nz0);
        int b10 = 0, c = 0;
        if (bal) { b10 = __ffsll(bal) - 1; c = __shfl(cum, b10); }
        const int fast = (bal != 0ull && c <= 64) ? 1 : 0;
        if (lane == 0) {
            meta_s[pt] = (b10 & 0xff) | ((fast ? c : 0) << 8)
                       | ((maxbin & 0xff) << 16) | (fast << 30);
        }
    }
    __syncthreads();                                      // B4
    const int meta = meta_s[pt];
    const int b10 = meta & 0xff;
    const int c = (meta >> 8) & 0xff;
    const int maxbin = (meta >> 16) & 0xff;
    const bool fast = ((meta >> 30) & 1) != 0;            // uniform per point

    if (fast) {
        // ---- ballot-base compaction of candidates (bin <= b10, c <= 64) ----
        #pragma unroll
        for (int s = 0; s < 4; ++s) {
            const bool pred = (q4[s] <= b10);
            const unsigned long long m = __ballot(pred);
            if (m) {
                int base = 0;
                if (lane == 0) base = atomicAdd(&ccnt[pt], __popcll(m));
                base = __shfl(base, 0);
                if (pred) {
                    const int pos = base + (int)__popcll(m & ((1ull << lane) - 1ull));
                    const int idx = jb + s * 64 + lane;
                    cand[pt][pos] = ((unsigned long long)__float_as_uint(d4[s]) << 32)
                                  | (unsigned)idx;
                }
            }
        }
    } else {
        // ---- fallback: per-wave top-10 into cand[pt][w*10..] ----
        unsigned valid = 0xfu;
        unsigned long long keep = 0;
        for (int r = 0; r < KNN; ++r) {
            float bv = FLT_MAX_;
            int bi = 0x7fffffff;
            #pragma unroll
            for (int s = 0; s < 4; ++s) {
                if (valid & (1u << s)) {
                    const float v_ = d4[s];
                    const int id_ = jb + s * 64 + lane;
                    if (v_ < bv || (v_ == bv && id_ < bi)) { bv = v_; bi = id_; }
                }
            }
            #pragma unroll
            for (int off = 32; off > 0; off >>= 1) {
                const float ov = __shfl_xor(bv, off);
                const int oi = __shfl_xor(bi, off);
                if (ov < bv || (ov == bv && oi < bi)) { bv = ov; bi = oi; }
            }
            const int loc = bi - jb;
            if (loc >= 0 && loc < 256 && lane == (loc & 63)) valid &= ~(1u << (loc >> 6));
            if (lane == r) keep = ((unsigned long long)__float_as_uint(bv) << 32)
                                | (unsigned)bi;
        }
        if (lane < KNN) cand[pt][w * KNN + lane] = keep;
    }
    __syncthreads();                                      // B5

    const int ncand = fast ? c : 4 * KNN;
    const int vsplit = (maxbin < 15) ? maxbin : 15;       // dot part-1 end
    float s = 0.0f;                                       // lives in waves 0-1

    // ---- seg A: wave2 rank-select || waves0-1 dot part 1 ----
    if (w == 2) {
        if (lane < ncand) {
            const unsigned long long my = cand[pt][lane];
            int rank = 0;
            #pragma unroll 8
            for (int pp = 0; pp < ncand; ++pp) {
                rank += (cand[pt][pp] < my) ? 1 : 0;
            }
            if (rank < KNN) nn[pt][rank] = (int)(my & 0xffffffffu);
        }
    } else if (w < 2) {
        const float* tdc = Td + t;                        // t<128 = channel
        #pragma unroll 4
        for (int v = 0; v <= vsplit; ++v) {
            s += (float)hist[v] * tdc[v * HID];           // zero bins add 0.0f
        }
    }
    __syncthreads();                                      // B6

    // ---- seg B: wave3 angles || waves0-1 dot part 2 ----
    if (w == 3) {
        unsigned mk = 0u;
        #pragma unroll
        for (int rep = 0; rep < 2; ++rep) {
            const int pr = lane + rep * 64;               // pair id
            const int valid_p = (pr < KNN * KNN);
            const int k = valid_p ? (pr / KNN) : 0;
            const int l = valid_p ? (pr % KNN) : 0;
            const int jk = nn[pt][k], jl = nn[pt][l];
            const float4 qk = P[jk];
            const float4 ql = P[jl];
            const float kx = qk.x - p.x;
            const float ky = qk.y - p.y;
            const float kz = qk.z - p.z;
            const float dk = sqrtf(kx * kx + ky * ky + kz * kz) + 1e-8f;
            const float lx = ql.x - p.x;
            const float ly = ql.y - p.y;
            const float lz = ql.z - p.z;
            const float dl = sqrtf(lx * lx + ly * ly + lz * lz) + 1e-8f;
            float cc = (kx / dk) * (lx / dl) + (ky / dk) * (ly / dl)
                     + (kz / dk) * (lz / dl);
            cc = fminf(fmaxf(cc, -1.0f), 1.0f);
            const float ang = acosf(cc);
            float q = rintf(ang * (float)(180.0 / (15.0 * M_PI)));
            q = fminf(fmaxf(q, 0.0f), 15.0f);
            if (valid_p) mk |= 1u << (int)q;
        }
        #pragma unroll
        for (int off = 32; off > 0; off >>= 1) mk |= __shfl_xor(mk, off);
        if (lane == 0) amask_s[pt] = mk;                  // plain store
    } else if (w < 2) {
        const float* tdc = Td + t;
        #pragma unroll 4
        for (int v = 16; v <= maxbin; ++v) {
            s += (float)hist[v] * tdc[v * HID];
        }
    }
    __syncthreads();                                      // B7

    // ---- seg C: waves0-1 Ta-max + direct write ----
    if (t < HID) {
        const unsigned am = amask_s[pt];
        float mx = -FLT_MAX_;
        const float* tac = Ta + t;
        #pragma unroll
        for (int v = 0; v < 16; ++v) {
            const float tv = tac[v * HID];
            if (am & (1u << v)) mx = fmaxf(mx, tv);
        }
        out[(size_t)gid * HID + t] = s + mx;
    }
}

// ---------------------------------------------------------------------------
// Fallback single-point kernel (R10, proven) for nP not divisible by PPB.
// ---------------------------------------------------------------------------
__global__ __launch_bounds__(256, 8) void gse_main(
    const float4* __restrict__ P4,
    const float* __restrict__ Td,
    const float* __restrict__ Ta,
    float* __restrict__ out) {
    const int gid = blockIdx.x;
    const int b = gid >> 10;
    const int i = gid & 1023;
    const float4* P = P4 + (size_t)b * NPTS;
    const int tid = threadIdx.x;
    const int lane = tid & 63;
    const int w = tid >> 6;

    __shared__ int h4[4][256];
    __shared__ unsigned long long cand[64];
    __shared__ int nn[KNN];
    __shared__ float sums[256], mxs[256];
    __shared__ unsigned amask_s;
    __shared__ int ccnt;
    __shared__ int meta_s;

    {
        int* hf = (int*)h4;
        hf[tid] = 0; hf[tid + 256] = 0; hf[tid + 512] = 0; hf[tid + 768] = 0;
    }
    if (tid == 0) { amask_s = 0u; ccnt = 0; }
    const float4 p = P[i];
    __syncthreads();

    float d4[4];
    int q4[4];
    const int jb = w * 256;
    #pragma unroll
    for (int s = 0; s < 4; ++s) {
        const int j = jb + s * 64 + lane;
        const float4 q = P[j];
        const float dx = p.x - q.x;
        const float dy = p.y - q.y;
        const float dz = p.z - q.z;
        const float dd = sqrtf(dx * dx + dy * dy + dz * dz);
        d4[s] = dd;
        float qq = rintf(dd / 0.2f);
        qq = fminf(fmaxf(qq, 0.0f), 255.0f);
        q4[s] = (int)qq;
        atomicAdd(&h4[w][q4[s]], 1);
    }
    __syncthreads();

    const int hsum = h4[0][tid] + h4[1][tid] + h4[2][tid] + h4[3][tid];
    h4[0][tid] = hsum;
    __syncthreads();
    const int* hist = h4[0];

    if (w == 0) {
        int cum = hist[lane];
        #pragma unroll
        for (int off = 1; off < 64; off <<= 1) {
            const int n_ = __shfl_up(cum, off);
            if (lane >= off) cum += n_;
        }
        const unsigned long long bal = __ballot(cum >= KNN);
        const unsigned long long nz0 = __ballot(hist[lane] != 0);
        const unsigned long long nz1 = __ballot(hist[64 + lane] != 0);
        const unsigned long long nz2 = __ballot(hist[128 + lane] != 0);
        const unsigned long long nz3 = __ballot(hist[192 + lane] != 0);
        int maxbin;
        if (nz3)      maxbin = 192 + 63 - __clzll((long long)nz3);
        else if (nz2) maxbin = 128 + 63 - __clzll((long long)nz2);
        else if (nz1) maxbin = 64 + 63 - __clzll((long long)nz1);
        else          maxbin = 63 - __clzll((long long)nz0);
        int b10 = 0, c = 0;
        if (bal) { b10 = __ffsll(bal) - 1; c = __shfl(cum, b10); }
        const int fast = (bal != 0ull && c <= 64) ? 1 : 0;
        if (lane == 0) {
            meta_s = (b10 & 0xff) | ((fast ? c : 0) << 8)
                   | ((maxbin & 0xff) << 16) | (fast << 30);
        }
    }
    __syncthreads();
    const int meta = meta_s;
    const int b10 = meta & 0xff;
    const int c = (meta >> 8) & 0xff;
    const int maxbin = (meta >> 16) & 0xff;
    const bool fast = ((meta >> 30) & 1) != 0;

    if (fast) {
        #pragma unroll
        for (int s = 0; s < 4; ++s) {
            const bool pred = (q4[s] <= b10);
            const unsigned long long m = __ballot(pred);
            if (m) {
                int base = 0;
                if (lane == 0) base = atomicAdd(&ccnt, __popcll(m));
                base = __shfl(base, 0);
                if (pred) {
                    const int pos = base + (int)__popcll(m & ((1ull << lane) - 1ull));
                    const int idx = jb + s * 64 + lane;
                    cand[pos] = ((unsigned long long)__float_as_uint(d4[s]) << 32)
                              | (unsigned)idx;
                }
            }
        }
        __syncthreads();
        if (tid < c) {
            const unsigned long long my = cand[tid];
            int rank = 0;
            #pragma unroll 8
            for (int pp = 0; pp < c; ++pp) rank += (cand[pp] < my) ? 1 : 0;
            if (rank < KNN) nn[rank] = (int)(my & 0xffffffffu);
        }
        __syncthreads();
    } else {
        unsigned valid = 0xfu;
        unsigned long long keep = 0;
        for (int r = 0; r < KNN; ++r) {
            float bv = FLT_MAX_;
            int bi = 0x7fffffff;
            #pragma unroll
            for (int s = 0; s < 4; ++s) {
                if (valid & (1u << s)) {
                    const float v_ = d4[s];
                    const int id_ = jb + s * 64 + lane;
                    if (v_ < bv || (v_ == bv && id_ < bi)) { bv = v_; bi = id_; }
                }
            }
            #pragma unroll
            for (int off = 32; off > 0; off >>= 1) {
                const float ov = __shfl_xor(bv, off);
                const int oi = __shfl_xor(bi, off);
                if (ov < bv || (ov == bv && oi < bi)) { bv = ov; bi = oi; }
            }
            const int loc = bi - jb;
            if (loc >= 0 && loc < 256 && lane == (loc & 63)) valid &= ~(1u << (loc >> 6));
            if (lane == r) keep = ((unsigned long long)__float_as_uint(bv) << 32)
                                | (unsigned)bi;
        }
        if (lane < KNN) cand[w * KNN + lane] = keep;
        __syncthreads();
        if (tid < 4 * KNN) {
            const unsigned long long my = cand[tid];
            int rank = 0;
            for (int pp = 0; pp < 4 * KNN; ++pp) rank += (cand[pp] < my) ? 1 : 0;
            if (rank < KNN) nn[rank] = (int)(my & 0xffffffffu);
        }
        __syncthreads();
    }

    if (tid < KNN * KNN) {
        const int k = tid / KNN, l = tid % KNN;
        const int jk = nn[k], jl = nn[l];
        const float4 qk = P[jk];
        const float4 ql = P[jl];
        const float kx = qk.x - p.x;
        const float ky = qk.y - p.y;
        const float kz = qk.z - p.z;
        const float dk = sqrtf(kx * kx + ky * ky + kz * kz) + 1e-8f;
        const float lx = ql.x - p.x;
        const float ly = ql.y - p.y;
        const float lz = ql.z - p.z;
        const float dl = sqrtf(lx * lx + ly * ly + lz * lz) + 1e-8f;
        float cc = (kx / dk) * (lx / dl) + (ky / dk) * (ly / dl) + (kz / dk) * (lz / dl);
        cc = fminf(fmaxf(cc, -1.0f), 1.0f);
        const float ang = acosf(cc);
        float q = rintf(ang * (float)(180.0 / (15.0 * M_PI)));
        q = fminf(fmaxf(q, 0.0f), 15.0f);
        atomicOr(&amask_s, 1u << (int)q);
    }
    __syncthreads();

    const unsigned am = amask_s;
    const int c7 = tid & 127;
    const int half = tid >> 7;
    float s = 0.0f;
    const float* tdc = Td + c7;
    #pragma unroll 4
    for (int v = half; v <= maxbin; v += 2) {
        s += (float)hist[v] * tdc[v * HID];
    }
    float mx = -FLT_MAX_;
    const float* tac = Ta + c7;
    #pragma unroll
    for (int v = 0; v < 8; ++v) {
        const int vv = half * 8 + v;
        const float tv = tac[vv * HID];
        if (am & (1u << vv)) mx = fmaxf(mx, tv);
    }
    sums[tid] = s;
    mxs[tid] = mx;
    __syncthreads();
    if (tid < HID) {
        out[(size_t)gid * HID + tid] =
            (sums[tid] + sums[tid + 128]) + fmaxf(mxs[tid], mxs[tid + 128]);
    }
}

extern "C" void kernel_launch(void* const* d_in, const int* in_sizes, int n_in,
                              void* d_out, int out_size, void* d_ws, size_t ws_size,
                              hipStream_t stream) {
    const float* pts = (const float*)d_in[0];
    const float* Wd  = (const float*)d_in[1];
    const float* bd  = (const float*)d_in[2];
    const float* Wa  = (const float*)d_in[3];
    const float* ba  = (const float*)d_in[4];
    float* out = (float*)d_out;

    const int B = in_sizes[0] / (NPTS * 3);
    const int nP = B * NPTS;

    float* Td = (float*)d_ws;                        // 256*128*4 = 128 KiB
    float* Ta = Td + 256 * HID;                      // 16*128*4  =   8 KiB
    float4* P4 = (float4*)(Ta + 16 * HID);           // nP*16 B

    gse_build<<<256, 512, 0, stream>>>(Wd, bd, Wa, ba, pts, nP, Td, Ta, P4);
    if (nP % PPB == 0) {
        gse_main2<<<nP / PPB, PPB * 256, 0, stream>>>(P4, Td, Ta, out);
    } else {
        gse_main<<<nP, 256, 0, stream>>>(P4, Td, Ta, out);
    }
}

// Round 13
// 20.383 us; speedup vs baseline: 1.0709x; 1.0354x over previous
//
#include <hip/hip_runtime.h>
#include <hip/hip_bf16.h>

#define NPTS 1024
#define HID 128
#define KNN 10
#define PPB 2                  // points per block (block = PPB*256 threads)
#define FLT_MAX_ 3.402823466e+38f

// ---------------------------------------------------------------------------
// Kernel 1 (R10, proven): build LUTs (epilogue folded) + repack points.
//   Td[v][c] = (sinusoid(v).Wd[c] + bd[c]) / 1024,  v in [0,256)
//   Ta[v][c] =  sinusoid(v).Wa[c] + ba[c],          v in [0,16)
//   P4[j]    = (x,y,z,0)
// grid: 272 blocks x 512 threads (512-thr blocks run 4/CU; no extra round).
// ---------------------------------------------------------------------------
__global__ __launch_bounds__(512) void gse_build(
    const float* __restrict__ Wd, const float* __restrict__ bd,
    const float* __restrict__ Wa, const float* __restrict__ ba,
    const float* __restrict__ pts, int nP,
    float* __restrict__ Td, float* __restrict__ Ta, float4* __restrict__ P4) {
    const int blk = blockIdx.x;
    const int tid = threadIdx.x;

    // folded repack: 8 points per block per pass, strided for any nP
    if (tid < 8) {
        for (int idx = blk * 8 + tid; idx < nP; idx += 272 * 8) {
            P4[idx] = make_float4(pts[idx * 3 + 0], pts[idx * 3 + 1],
                                  pts[idx * 3 + 2], 0.0f);
        }
    }

    __shared__ float S[HID];
    __shared__ float part[512];
    const bool isA = (blk >= 256);
    const int v = isA ? blk - 256 : blk;
    const int c = tid & 127;
    const int seg = tid >> 7;               // 0..3

    if (tid < HID) {
        const int m = tid >> 1;
        const float dtm = expf((float)m * (float)(-9.210340371976184 / 64.0));
        const float arg = (float)v * dtm;
        S[tid] = (tid & 1) ? cosf(arg) : sinf(arg);
    }
    __syncthreads();

    const float* W = isA ? Wa : Wd;
    const float* wrow = W + c * HID + seg * 32;
    const float* srow = S + seg * 32;
    float acc = 0.0f;
    #pragma unroll
    for (int h = 0; h < 32; h += 4) {
        const float4 wv = *reinterpret_cast<const float4*>(wrow + h);
        acc += srow[h] * wv.x + srow[h + 1] * wv.y + srow[h + 2] * wv.z + srow[h + 3] * wv.w;
    }
    part[tid] = acc;
    __syncthreads();

    if (tid < HID) {
        const float s = (part[c] + part[c + 128]) + (part[c + 256] + part[c + 384]);
        if (isA) Ta[v * HID + c] = s + ba[c];
        else     Td[v * HID + c] = (s + bd[c]) * (1.0f / (float)NPTS);
    }
}

// ---------------------------------------------------------------------------
// Kernel 2: TWO points per block (512 threads = 2 x 4 waves), grid = nP/2.
//   = R10's 20.1us kernel with three strict-trim changes:
//   (1) no init barrier: each wave zeroes its OWN hist slice (same-wave LDS
//       ops are in-order);
//   (2) hist merge for phase 5 runs on waves 1-2 CONCURRENTLY with wave 0's
//       scan/ballots (wave 0 reads the 4 raw hists directly) -> merge barrier
//       deleted;
//   (3) fused angle stage (per-pair unit-vector recompute, bit-identical,
//       validated R11/R12) -> unit-vector phase + barrier deleted.
//   6 block barriers (R10 had 9). Barrier count identical on fast/fallback.
// ---------------------------------------------------------------------------
__global__ __launch_bounds__(512, 8) void gse_main2(
    const float4* __restrict__ P4,      // (nP)
    const float* __restrict__ Td,       // (256, 128)
    const float* __restrict__ Ta,       // (16, 128)
    float* __restrict__ out) {          // (nP, 128)
    const int tid = threadIdx.x;        // 0..511
    const int pt  = tid >> 8;           // 0..1  (point slot)
    const int t   = tid & 255;          // thread within point
    const int lane = tid & 63;
    const int w   = (tid >> 6) & 3;     // wave within point
    const int gid = blockIdx.x * PPB + pt;

    const int b = gid >> 10;
    const int i = gid & 1023;
    const float4* P = P4 + (size_t)b * NPTS;

    __shared__ int h4[PPB][4][256];
    __shared__ int hm[PPB][256];        // merged hist (for phase 5)
    __shared__ unsigned long long cand[PPB][64];
    __shared__ int nn[PPB][KNN];
    __shared__ float sums[PPB][256], mxs[PPB][256];
    __shared__ unsigned amask_s[PPB];
    __shared__ int ccnt[PPB];
    __shared__ int meta_s[PPB];

    // ---- each wave zeroes its OWN hist slice (no barrier needed) ----
    #pragma unroll
    for (int k = 0; k < 4; ++k) h4[pt][w][lane + k * 64] = 0;
    if (t == 0) { amask_s[pt] = 0u; ccnt[pt] = 0; }
    const float4 p = P[i];

    // ---- phase 1: 4 distances/lane + per-wave private hist ----
    float d4[4];
    int q4[4];
    const int jb = w * 256;
    #pragma unroll
    for (int s = 0; s < 4; ++s) {
        const int j = jb + s * 64 + lane;
        const float4 q = P[j];
        const float dx = p.x - q.x;
        const float dy = p.y - q.y;
        const float dz = p.z - q.z;
        const float dd = sqrtf(dx * dx + dy * dy + dz * dz);
        d4[s] = dd;
        float qq = rintf(dd / 0.2f);    // matches jnp.round (half-to-even)
        qq = fminf(fmaxf(qq, 0.0f), 255.0f);
        q4[s] = (int)qq;
        atomicAdd(&h4[pt][w][q4[s]], 1);
    }
    __syncthreads();                                      // B1: hists done

    // ---- concurrent: wave0 scan/ballots (raw hists) || waves1-2 merge ----
    if (w == 0) {
        const int* H0 = h4[pt][0];
        const int* H1 = h4[pt][1];
        const int* H2 = h4[pt][2];
        const int* H3 = h4[pt][3];
        const int hv0 = H0[lane] + H1[lane] + H2[lane] + H3[lane];
        int cum = hv0;
        #pragma unroll
        for (int off = 1; off < 64; off <<= 1) {
            const int n_ = __shfl_up(cum, off);
            if (lane >= off) cum += n_;
        }
        const unsigned long long bal = __ballot(cum >= KNN);
        const int hv1 = H0[64 + lane] + H1[64 + lane] + H2[64 + lane] + H3[64 + lane];
        const int hv2 = H0[128 + lane] + H1[128 + lane] + H2[128 + lane] + H3[128 + lane];
        const int hv3 = H0[192 + lane] + H1[192 + lane] + H2[192 + lane] + H3[192 + lane];
        const unsigned long long nz0 = __ballot(hv0 != 0);
        const unsigned long long nz1 = __ballot(hv1 != 0);
        const unsigned long long nz2 = __ballot(hv2 != 0);
        const unsigned long long nz3 = __ballot(hv3 != 0);
        int maxbin;
        if (nz3)      maxbin = 192 + 63 - __clzll((long long)nz3);
        else if (nz2) maxbin = 128 + 63 - __clzll((long long)nz2);
        else if (nz1) maxbin = 64 + 63 - __clzll((long long)nz1);
        else          maxbin = 63 - __clzll((long long)nz0);
        int b10 = 0, c = 0;
        if (bal) { b10 = __ffsll(bal) - 1; c = __shfl(cum, b10); }
        const int fast = (bal != 0ull && c <= 64) ? 1 : 0;
        if (lane == 0) {
            meta_s[pt] = (b10 & 0xff) | ((fast ? c : 0) << 8)
                       | ((maxbin & 0xff) << 16) | (fast << 30);
        }
    } else if (w == 1) {
        #pragma unroll
        for (int k = 0; k < 2; ++k) {
            const int v = lane + k * 64;
            hm[pt][v] = h4[pt][0][v] + h4[pt][1][v] + h4[pt][2][v] + h4[pt][3][v];
        }
    } else if (w == 2) {
        #pragma unroll
        for (int k = 2; k < 4; ++k) {
            const int v = lane + k * 64;
            hm[pt][v] = h4[pt][0][v] + h4[pt][1][v] + h4[pt][2][v] + h4[pt][3][v];
        }
    }
    __syncthreads();                                      // B2: meta + hm ready
    const int meta = meta_s[pt];
    const int b10 = meta & 0xff;
    const int c = (meta >> 8) & 0xff;
    const int maxbin = (meta >> 16) & 0xff;
    const bool fast = ((meta >> 30) & 1) != 0;            // uniform per point

    if (fast) {
        // ---- ballot-base compaction of candidates (bin <= b10, c <= 64) ----
        #pragma unroll
        for (int s = 0; s < 4; ++s) {
            const bool pred = (q4[s] <= b10);
            const unsigned long long m = __ballot(pred);
            if (m) {
                int base = 0;
                if (lane == 0) base = atomicAdd(&ccnt[pt], __popcll(m));
                base = __shfl(base, 0);
                if (pred) {
                    const int pos = base + (int)__popcll(m & ((1ull << lane) - 1ull));
                    const int idx = jb + s * 64 + lane;
                    cand[pt][pos] = ((unsigned long long)__float_as_uint(d4[s]) << 32)
                                  | (unsigned)idx;
                }
            }
        }
    } else {
        // ---- fallback: per-wave top-10 into cand[pt][w*10..] ----
        unsigned valid = 0xfu;
        unsigned long long keep = 0;
        for (int r = 0; r < KNN; ++r) {
            float bv = FLT_MAX_;
            int bi = 0x7fffffff;
            #pragma unroll
            for (int s = 0; s < 4; ++s) {
                if (valid & (1u << s)) {
                    const float v_ = d4[s];
                    const int id_ = jb + s * 64 + lane;
                    if (v_ < bv || (v_ == bv && id_ < bi)) { bv = v_; bi = id_; }
                }
            }
            #pragma unroll
            for (int off = 32; off > 0; off >>= 1) {
                const float ov = __shfl_xor(bv, off);
                const int oi = __shfl_xor(bi, off);
                if (ov < bv || (ov == bv && oi < bi)) { bv = ov; bi = oi; }
            }
            const int loc = bi - jb;
            if (loc >= 0 && loc < 256 && lane == (loc & 63)) valid &= ~(1u << (loc >> 6));
            if (lane == r) keep = ((unsigned long long)__float_as_uint(bv) << 32)
                                | (unsigned)bi;
        }
        if (lane < KNN) cand[pt][w * KNN + lane] = keep;
    }
    __syncthreads();                                      // B3: cand staged

    // ---- rank-select top-10 (wave 0 of each point; ncand <= 64) ----
    const int ncand = fast ? c : 4 * KNN;
    if (t < ncand) {
        const unsigned long long my = cand[pt][t];
        int rank = 0;
        #pragma unroll 8
        for (int pp = 0; pp < ncand; ++pp) {
            rank += (cand[pt][pp] < my) ? 1 : 0;
        }
        if (rank < KNN) nn[pt][rank] = (int)(my & 0xffffffffu);
    }
    __syncthreads();                                      // B4: nn ready

    // ---- fused angles: each pair recomputes both unit vectors ----
    if (t < KNN * KNN) {
        const int k = t / KNN, l = t % KNN;
        const int jk = nn[pt][k], jl = nn[pt][l];
        const float4 qk = P[jk];
        const float4 ql = P[jl];
        const float kx = qk.x - p.x;
        const float ky = qk.y - p.y;
        const float kz = qk.z - p.z;
        const float dk = sqrtf(kx * kx + ky * ky + kz * kz) + 1e-8f;
        const float lx = ql.x - p.x;
        const float ly = ql.y - p.y;
        const float lz = ql.z - p.z;
        const float dl = sqrtf(lx * lx + ly * ly + lz * lz) + 1e-8f;
        float cc = (kx / dk) * (lx / dl) + (ky / dk) * (ly / dl) + (kz / dk) * (lz / dl);
        cc = fminf(fmaxf(cc, -1.0f), 1.0f);
        const float ang = acosf(cc);
        float q = rintf(ang * (float)(180.0 / (15.0 * M_PI)));
        q = fminf(fmaxf(q, 0.0f), 15.0f);
        atomicOr(&amask_s[pt], 1u << (int)q);
    }
    __syncthreads();                                      // B5: amask ready

    // ---- phase 5: split even/odd bins + low/high mask across half-points ----
    const unsigned am = amask_s[pt];
    const int c7 = t & 127;
    const int half = t >> 7;
    float s = 0.0f;
    const float* tdc = Td + c7;
    #pragma unroll 4
    for (int v = half; v <= maxbin; v += 2) {
        s += (float)hm[pt][v] * tdc[v * HID];   // zero bins add exact 0.0f
    }
    float mx = -FLT_MAX_;
    const float* tac = Ta + c7;
    #pragma unroll
    for (int v = 0; v < 8; ++v) {
        const int vv = half * 8 + v;
        const float tv = tac[vv * HID];
        if (am & (1u << vv)) mx = fmaxf(mx, tv);
    }
    sums[pt][t] = s;
    mxs[pt][t] = mx;
    __syncthreads();                                      // B6: partials staged
    if (t < HID) {
        out[(size_t)gid * HID + t] =
            (sums[pt][t] + sums[pt][t + 128]) + fmaxf(mxs[pt][t], mxs[pt][t + 128]);
    }
}

// ---------------------------------------------------------------------------
// Fallback single-point kernel (proven) for nP not divisible by PPB.
// ---------------------------------------------------------------------------
__global__ __launch_bounds__(256, 8) void gse_main(
    const float4* __restrict__ P4,
    const float* __restrict__ Td,
    const float* __restrict__ Ta,
    float* __restrict__ out) {
    const int gid = blockIdx.x;
    const int b = gid >> 10;
    const int i = gid & 1023;
    const float4* P = P4 + (size_t)b * NPTS;
    const int tid = threadIdx.x;
    const int lane = tid & 63;
    const int w = tid >> 6;

    __shared__ int h4[4][256];
    __shared__ unsigned long long cand[64];
    __shared__ int nn[KNN];
    __shared__ float sums[256], mxs[256];
    __shared__ unsigned amask_s;
    __shared__ int ccnt;
    __shared__ int meta_s;

    {
        int* hf = (int*)h4;
        hf[tid] = 0; hf[tid + 256] = 0; hf[tid + 512] = 0; hf[tid + 768] = 0;
    }
    if (tid == 0) { amask_s = 0u; ccnt = 0; }
    const float4 p = P[i];
    __syncthreads();

    float d4[4];
    int q4[4];
    const int jb = w * 256;
    #pragma unroll
    for (int s = 0; s < 4; ++s) {
        const int j = jb + s * 64 + lane;
        const float4 q = P[j];
        const float dx = p.x - q.x;
        const float dy = p.y - q.y;
        const float dz = p.z - q.z;
        const float dd = sqrtf(dx * dx + dy * dy + dz * dz);
        d4[s] = dd;
        float qq = rintf(dd / 0.2f);
        qq = fminf(fmaxf(qq, 0.0f), 255.0f);
        q4[s] = (int)qq;
        atomicAdd(&h4[w][q4[s]], 1);
    }
    __syncthreads();

    const int hsum = h4[0][tid] + h4[1][tid] + h4[2][tid] + h4[3][tid];
    h4[0][tid] = hsum;
    __syncthreads();
    const int* hist = h4[0];

    if (w == 0) {
        int cum = hist[lane];
        #pragma unroll
        for (int off = 1; off < 64; off <<= 1) {
            const int n_ = __shfl_up(cum, off);
            if (lane >= off) cum += n_;
        }
        const unsigned long long bal = __ballot(cum >= KNN);
        const unsigned long long nz0 = __ballot(hist[lane] != 0);
        const unsigned long long nz1 = __ballot(hist[64 + lane] != 0);
        const unsigned long long nz2 = __ballot(hist[128 + lane] != 0);
        const unsigned long long nz3 = __ballot(hist[192 + lane] != 0);
        int maxbin;
        if (nz3)      maxbin = 192 + 63 - __clzll((long long)nz3);
        else if (nz2) maxbin = 128 + 63 - __clzll((long long)nz2);
        else if (nz1) maxbin = 64 + 63 - __clzll((long long)nz1);
        else          maxbin = 63 - __clzll((long long)nz0);
        int b10 = 0, c = 0;
        if (bal) { b10 = __ffsll(bal) - 1; c = __shfl(cum, b10); }
        const int fast = (bal != 0ull && c <= 64) ? 1 : 0;
        if (lane == 0) {
            meta_s = (b10 & 0xff) | ((fast ? c : 0) << 8)
                   | ((maxbin & 0xff) << 16) | (fast << 30);
        }
    }
    __syncthreads();
    const int meta = meta_s;
    const int b10 = meta & 0xff;
    const int c = (meta >> 8) & 0xff;
    const int maxbin = (meta >> 16) & 0xff;
    const bool fast = ((meta >> 30) & 1) != 0;

    if (fast) {
        #pragma unroll
        for (int s = 0; s < 4; ++s) {
            const bool pred = (q4[s] <= b10);
            const unsigned long long m = __ballot(pred);
            if (m) {
                int base = 0;
                if (lane == 0) base = atomicAdd(&ccnt, __popcll(m));
                base = __shfl(base, 0);
                if (pred) {
                    const int pos = base + (int)__popcll(m & ((1ull << lane) - 1ull));
                    const int idx = jb + s * 64 + lane;
                    cand[pos] = ((unsigned long long)__float_as_uint(d4[s]) << 32)
                              | (unsigned)idx;
                }
            }
        }
        __syncthreads();
        if (tid < c) {
            const unsigned long long my = cand[tid];
            int rank = 0;
            #pragma unroll 8
            for (int pp = 0; pp < c; ++pp) rank += (cand[pp] < my) ? 1 : 0;
            if (rank < KNN) nn[rank] = (int)(my & 0xffffffffu);
        }
        __syncthreads();
    } else {
        unsigned valid = 0xfu;
        unsigned long long keep = 0;
        for (int r = 0; r < KNN; ++r) {
            float bv = FLT_MAX_;
            int bi = 0x7fffffff;
            #pragma unroll
            for (int s = 0; s < 4; ++s) {
                if (valid & (1u << s)) {
                    const float v_ = d4[s];
                    const int id_ = jb + s * 64 + lane;
                    if (v_ < bv || (v_ == bv && id_ < bi)) { bv = v_; bi = id_; }
                }
            }
            #pragma unroll
            for (int off = 32; off > 0; off >>= 1) {
                const float ov = __shfl_xor(bv, off);
                const int oi = __shfl_xor(bi, off);
                if (ov < bv || (ov == bv && oi < bi)) { bv = ov; bi = oi; }
            }
            const int loc = bi - jb;
            if (loc >= 0 && loc < 256 && lane == (loc & 63)) valid &= ~(1u << (loc >> 6));
            if (lane == r) keep = ((unsigned long long)__float_as_uint(bv) << 32)
                                | (unsigned)bi;
        }
        if (lane < KNN) cand[w * KNN + lane] = keep;
        __syncthreads();
        if (tid < 4 * KNN) {
            const unsigned long long my = cand[tid];
            int rank = 0;
            for (int pp = 0; pp < 4 * KNN; ++pp) rank += (cand[pp] < my) ? 1 : 0;
            if (rank < KNN) nn[rank] = (int)(my & 0xffffffffu);
        }
        __syncthreads();
    }

    if (tid < KNN * KNN) {
        const int k = tid / KNN, l = tid % KNN;
        const int jk = nn[k], jl = nn[l];
        const float4 qk = P[jk];
        const float4 ql = P[jl];
        const float kx = qk.x - p.x;
        const float ky = qk.y - p.y;
        const float kz = qk.z - p.z;
        const float dk = sqrtf(kx * kx + ky * ky + kz * kz) + 1e-8f;
        const float lx = ql.x - p.x;
        const float ly = ql.y - p.y;
        const float lz = ql.z - p.z;
        const float dl = sqrtf(lx * lx + ly * ly + lz * lz) + 1e-8f;
        float cc = (kx / dk) * (lx / dl) + (ky / dk) * (ly / dl) + (kz / dk) * (lz / dl);
        cc = fminf(fmaxf(cc, -1.0f), 1.0f);
        const float ang = acosf(cc);
        float q = rintf(ang * (float)(180.0 / (15.0 * M_PI)));
        q = fminf(fmaxf(q, 0.0f), 15.0f);
        atomicOr(&amask_s, 1u << (int)q);
    }
    __syncthreads();

    const unsigned am = amask_s;
    const int c7 = tid & 127;
    const int half = tid >> 7;
    float s = 0.0f;
    const float* tdc = Td + c7;
    #pragma unroll 4
    for (int v = half; v <= maxbin; v += 2) {
        s += (float)hist[v] * tdc[v * HID];
    }
    float mx = -FLT_MAX_;
    const float* tac = Ta + c7;
    #pragma unroll
    for (int v = 0; v < 8; ++v) {
        const int vv = half * 8 + v;
        const float tv = tac[vv * HID];
        if (am & (1u << vv)) mx = fmaxf(mx, tv);
    }
    sums[tid] = s;
    mxs[tid] = mx;
    __syncthreads();
    if (tid < HID) {
        out[(size_t)gid * HID + tid] =
            (sums[tid] + sums[tid + 128]) + fmaxf(mxs[tid], mxs[tid + 128]);
    }
}

extern "C" void kernel_launch(void* const* d_in, const int* in_sizes, int n_in,
                              void* d_out, int out_size, void* d_ws, size_t ws_size,
                              hipStream_t stream) {
    const float* pts = (const float*)d_in[0];
    const float* Wd  = (const float*)d_in[1];
    const float* bd  = (const float*)d_in[2];
    const float* Wa  = (const float*)d_in[3];
    const float* ba  = (const float*)d_in[4];
    float* out = (float*)d_out;

    const int B = in_sizes[0] / (NPTS * 3);
    const int nP = B * NPTS;

    float* Td = (float*)d_ws;                        // 256*128*4 = 128 KiB
    float* Ta = Td + 256 * HID;                      // 16*128*4  =   8 KiB
    float4* P4 = (float4*)(Ta + 16 * HID);           // nP*16 B

    gse_build<<<272, 512, 0, stream>>>(Wd, bd, Wa, ba, pts, nP, Td, Ta, P4);
    if (nP % PPB == 0) {
        gse_main2<<<nP / PPB, PPB * 256, 0, stream>>>(P4, Td, Ta, out);
    } else {
        gse_main<<<nP, 256, 0, stream>>>(P4, Td, Ta, out);
    }
}